// Round 2
// baseline (307.483 us; speedup 1.0000x reference)
//
#include <hip/hip_runtime.h>
#include <math.h>

// PoseMLP: out = norm-quat( relu(relu(x@W1^T+b1)@W2^T+b2)@W3^T + b3 )
// B = 2097152 rows, fp32 everywhere.
//
// Design (R1 resubmit — previous round died on container infra, no data):
//  - 1 thread per row; h1[64], h2[64] held in VGPRs with ALL loops fully
//    unrolled so every array index is compile-time (runtime-indexed
//    arrays go to scratch on gfx950 — rule #20).
//  - Weights/biases are wave-uniform addresses -> LLVM promotes to s_load
//    (SMEM, K$-cached); inner loop should be v_fmac_f32 vdst, sgpr, vgpr.
//  - Compute-bound: 20.9 GFLOP fp32 vs 117 MB traffic.

__global__ __launch_bounds__(256) void pose_mlp_f32(
    const float* __restrict__ x,
    const float* __restrict__ W1, const float* __restrict__ b1,
    const float* __restrict__ W2, const float* __restrict__ b2,
    const float* __restrict__ W3, const float* __restrict__ b3,
    float* __restrict__ out, int nrows)
{
    const int row = blockIdx.x * 256 + threadIdx.x;
    if (row >= nrows) return;

    const float* xr = x + (size_t)row * 7;
    const float x0 = xr[0], x1 = xr[1], x2 = xr[2], x3 = xr[3],
                x4 = xr[4], x5 = xr[5], x6 = xr[6];

    // ---- Layer 1: 7 -> 64, ReLU ----
    float h1[64];
#pragma unroll
    for (int j = 0; j < 64; ++j) {
        const float* w = W1 + j * 7;
        float a = b1[j];
        a = fmaf(w[0], x0, a);
        a = fmaf(w[1], x1, a);
        a = fmaf(w[2], x2, a);
        a = fmaf(w[3], x3, a);
        a = fmaf(w[4], x4, a);
        a = fmaf(w[5], x5, a);
        a = fmaf(w[6], x6, a);
        h1[j] = fmaxf(a, 0.0f);
    }

    // ---- Layer 2: 64 -> 64, ReLU ----  (dominant: 4096 FMAs)
    float h2[64];
#pragma unroll
    for (int j = 0; j < 64; ++j) {
        const float* w = W2 + j * 64;
        float a = b2[j];
#pragma unroll
        for (int i = 0; i < 64; ++i)
            a = fmaf(w[i], h1[i], a);
        h2[j] = fmaxf(a, 0.0f);
    }

    // ---- Layer 3: 64 -> 7 ----
    float o[7];
#pragma unroll
    for (int j = 0; j < 7; ++j) {
        const float* w = W3 + j * 64;
        float a = b3[j];
#pragma unroll
        for (int i = 0; i < 64; ++i)
            a = fmaf(w[i], h2[i], a);
        o[j] = a;
    }

    // ---- Quat normalize (cols 3..6) ----
    const float s = fmaf(o[3], o[3], fmaf(o[4], o[4], fmaf(o[5], o[5], o[6] * o[6])));
    const float rn = 1.0f / sqrtf(s);

    float* orow = out + (size_t)row * 7;
    orow[0] = o[0];
    orow[1] = o[1];
    orow[2] = o[2];
    orow[3] = o[3] * rn;
    orow[4] = o[4] * rn;
    orow[5] = o[5] * rn;
    orow[6] = o[6] * rn;
}

extern "C" void kernel_launch(void* const* d_in, const int* in_sizes, int n_in,
                              void* d_out, int out_size, void* d_ws, size_t ws_size,
                              hipStream_t stream)
{
    const float* x  = (const float*)d_in[0];
    const float* W1 = (const float*)d_in[1];
    const float* b1 = (const float*)d_in[2];
    const float* W2 = (const float*)d_in[3];
    const float* b2 = (const float*)d_in[4];
    const float* W3 = (const float*)d_in[5];
    const float* b3 = (const float*)d_in[6];
    float* out = (float*)d_out;

    const int nrows = in_sizes[0] / 7;
    const int grid = (nrows + 255) / 256;
    pose_mlp_f32<<<grid, 256, 0, stream>>>(x, W1, b1, W2, b2, W3, b3, out, nrows);
}

// Round 5
// 181.146 us; speedup vs baseline: 1.6974x; 1.6974x over previous
//
#include <hip/hip_runtime.h>
#include <math.h>

// PoseMLP via split-f16 MFMA (R5 = R4 resubmit; container died, no data).
//
// Math: every matmul A*W^T is computed as 3 MFMA passes from a 2-way f16
// split: a = hi + lo*2^-12 (hi = RN_f16(a), lo = RN_f16((a-hi)*4096)).
// Kept products: (hi,hi)->acc_hi ; (hi,lo_s),(lo_s,hi)->acc_lo.
// result = acc_hi + acc_lo * 2^-12. Dropped lo*lo ~ 2^-24 relative.
// The 2^12 scaling keeps lo terms out of f16-denormal range.
//
// MFMA v_mfma_f32_32x32x16_f16 layouts assumed (m74/m101 C/D verified):
//   A (32x16): row = lane&31, k = 8*(lane>>5) + j   (j=0..7, f16x8)
//   B (16x32): col = lane&31, k = 8*(lane>>5) + j
//   C/D      : col = lane&31, row = (reg&3) + 8*(reg>>2) + 4*(lane>>5)
//
// Per wave per iter: 32 rows. L1: 6 MFMA, L2: 24, L3: 12.
// Layer transposes via wave-private LDS ([32][68] f32, stride 68 keeps
// ds_read_b128 bank-optimal). No __syncthreads anywhere (same-wave DS is
// in-order; sched_barrier(0) pins compiler order across cross-lane WAR).

typedef _Float16 half8  __attribute__((ext_vector_type(8)));
typedef float    floatx16 __attribute__((ext_vector_type(16)));
typedef float    floatx4  __attribute__((ext_vector_type(4)));

#define MFMA32(a, b, c) __builtin_amdgcn_mfma_f32_32x32x16_f16((a), (b), (c), 0, 0, 0)

struct Split { _Float16 hi, lo; };

static __device__ inline Split split_f16(float a) {
    Split s;
    _Float16 h = (_Float16)a;           // v_cvt_f16_f32 (RN)
    float r = a - (float)h;             // exact (Sterbenz)
    s.hi = h;
    s.lo = (_Float16)(r * 4096.0f);     // scaled by 2^12, avoids f16 denormals
    return s;
}

#define LO_SCALE 2.44140625e-4f  /* 2^-12 */

__global__ __launch_bounds__(256) void pose_mlp_mfma(
    const float* __restrict__ x,
    const float* __restrict__ W1, const float* __restrict__ b1,
    const float* __restrict__ W2, const float* __restrict__ b2,
    const float* __restrict__ W3, const float* __restrict__ b3,
    float* __restrict__ out, int nrows)
{
    const int tid  = threadIdx.x;
    const int lane = tid & 63;
    const int wv   = tid >> 6;
    const int g    = lane >> 5;   // k-group (0: k 0..7, 1: k 8..15)
    const int n5   = lane & 31;   // col index (neuron) / local row

    // Per-wave LDS: h tile [32][68] f32 (2176 dw) + o tile [32][8] (256 dw)
    __shared__ float lds[4 * 2432];
    float* hreg = &lds[wv * 2432];
    float* oreg = &lds[wv * 2432 + 2176];

    // ---------------- stationary weight fragments (per wave) ----------------
    // L2: B[k][n] = W2[n][k]; lane: n = ct*32+n5, k = kb*16 + g*8 + j
    half8 w2h[2][4], w2l[2][4];
#pragma unroll
    for (int ct = 0; ct < 2; ++ct) {
        const float* wrow = W2 + (ct * 32 + n5) * 64;
#pragma unroll
        for (int kb = 0; kb < 4; ++kb) {
            const floatx4* p = (const floatx4*)(wrow + kb * 16 + g * 8);
            floatx4 v0 = p[0], v1 = p[1];
#pragma unroll
            for (int j = 0; j < 8; ++j) {
                float a = (j < 4) ? v0[j] : v1[j - 4];
                Split s = split_f16(a);
                w2h[ct][kb][j] = s.hi;
                w2l[ct][kb][j] = s.lo;
            }
        }
    }
    // L3: B[k][n] = W3[n][k], valid cols n<7
    const bool nv = (n5 < 7);
    half8 w3h[4], w3l[4];
#pragma unroll
    for (int kb = 0; kb < 4; ++kb) {
        floatx4 v0 = {0.f, 0.f, 0.f, 0.f}, v1 = {0.f, 0.f, 0.f, 0.f};
        if (nv) {
            const floatx4* p = (const floatx4*)(W3 + n5 * 64 + kb * 16 + g * 8);
            v0 = p[0]; v1 = p[1];
        }
#pragma unroll
        for (int j = 0; j < 8; ++j) {
            float a = (j < 4) ? v0[j] : v1[j - 4];
            Split s = split_f16(a);
            w3h[kb][j] = s.hi;
            w3l[kb][j] = s.lo;
        }
    }
    // L1: B[k][n] = W1[n][k], K=7 padded to 16
    half8 w1h[2], w1l[2];
#pragma unroll
    for (int ct = 0; ct < 2; ++ct) {
        const float* wrow = W1 + (ct * 32 + n5) * 7;
#pragma unroll
        for (int j = 0; j < 8; ++j) {
            int k = g * 8 + j;
            float a = (k < 7) ? wrow[k] : 0.0f;
            Split s = split_f16(a);
            w1h[ct][j] = s.hi;
            w1l[ct][j] = s.lo;
        }
    }
    const float bias1[2] = { b1[n5], b1[n5 + 32] };
    const float bias2[2] = { b2[n5], b2[n5 + 32] };
    const float bias3    = nv ? b3[n5] : 0.0f;

    // ---------------- main loop: 8 iters x 128 rows/block ----------------
    const int blk0 = blockIdx.x * 1024;

    float xv[7] = {0.f,0.f,0.f,0.f,0.f,0.f,0.f};
    {   // prefetch iter 0 (rows blk0 + wv*32 + n5, g0 lanes only)
        int r = blk0 + wv * 32 + n5;
        if (g == 0 && r < nrows) {
            const float* xr = x + (size_t)r * 7;
#pragma unroll
            for (int j = 0; j < 7; ++j) xv[j] = xr[j];
        }
    }

    for (int it = 0; it < 8; ++it) {
        const int r0 = blk0 + it * 128 + wv * 32;

        // ---- X A-frags (only g0 lanes carry real k=0..6) ----
        half8 xh, xl;
#pragma unroll
        for (int j = 0; j < 8; ++j) {
            float a = (g == 0 && j < 7) ? xv[j] : 0.0f;
            Split s = split_f16(a);
            xh[j] = s.hi;
            xl[j] = s.lo;
        }
        // prefetch next iter's X
        if (it < 7) {
            int r = r0 + 128 + n5;
            if (g == 0 && r < nrows) {
                const float* xr = x + (size_t)r * 7;
#pragma unroll
                for (int j = 0; j < 7; ++j) xv[j] = xr[j];
            }
        }

        // ---- Layer 1: h1 = relu(X*W1^T + b1) ----
#pragma unroll
        for (int ct = 0; ct < 2; ++ct) {
            floatx16 ah, al;
#pragma unroll
            for (int i = 0; i < 16; ++i) { ah[i] = bias1[ct]; al[i] = 0.0f; }
            ah = MFMA32(xh, w1h[ct], ah);
            al = MFMA32(xh, w1l[ct], al);
            al = MFMA32(xl, w1h[ct], al);
#pragma unroll
            for (int i = 0; i < 16; ++i) {
                float v = fmaxf(fmaf(al[i], LO_SCALE, ah[i]), 0.0f);
                int row = (i & 3) + 8 * (i >> 2) + 4 * g;
                hreg[row * 68 + ct * 32 + n5] = v;
            }
        }
        __builtin_amdgcn_sched_barrier(0);

        // ---- h1 -> A-frags (transpose via LDS) ----
        half8 a2h[4], a2l[4];
#pragma unroll
        for (int kb = 0; kb < 4; ++kb) {
            const floatx4* p = (const floatx4*)&hreg[n5 * 68 + kb * 16 + g * 8];
            floatx4 v0 = p[0], v1 = p[1];
#pragma unroll
            for (int j = 0; j < 8; ++j) {
                float a = (j < 4) ? v0[j] : v1[j - 4];
                Split s = split_f16(a);
                a2h[kb][j] = s.hi;
                a2l[kb][j] = s.lo;
            }
        }
        __builtin_amdgcn_sched_barrier(0);

        // ---- Layer 2: h2 = relu(h1*W2^T + b2) (overwrites h tile) ----
#pragma unroll
        for (int ct = 0; ct < 2; ++ct) {
            floatx16 ch, cl;
#pragma unroll
            for (int i = 0; i < 16; ++i) { ch[i] = bias2[ct]; cl[i] = 0.0f; }
#pragma unroll
            for (int kb = 0; kb < 4; ++kb) {
                ch = MFMA32(a2h[kb], w2h[ct][kb], ch);
                cl = MFMA32(a2h[kb], w2l[ct][kb], cl);
                cl = MFMA32(a2l[kb], w2h[ct][kb], cl);
            }
#pragma unroll
            for (int i = 0; i < 16; ++i) {
                float v = fmaxf(fmaf(cl[i], LO_SCALE, ch[i]), 0.0f);
                int row = (i & 3) + 8 * (i >> 2) + 4 * g;
                hreg[row * 68 + ct * 32 + n5] = v;
            }
        }
        __builtin_amdgcn_sched_barrier(0);

        // ---- h2 -> A-frags ----
        half8 a3h[4], a3l[4];
#pragma unroll
        for (int kb = 0; kb < 4; ++kb) {
            const floatx4* p = (const floatx4*)&hreg[n5 * 68 + kb * 16 + g * 8];
            floatx4 v0 = p[0], v1 = p[1];
#pragma unroll
            for (int j = 0; j < 8; ++j) {
                float a = (j < 4) ? v0[j] : v1[j - 4];
                Split s = split_f16(a);
                a3h[kb][j] = s.hi;
                a3l[kb][j] = s.lo;
            }
        }
        __builtin_amdgcn_sched_barrier(0);

        // ---- Layer 3: o = h2*W3^T + b3 (cols 0..6 valid) ----
        {
            floatx16 oh, ol;
#pragma unroll
            for (int i = 0; i < 16; ++i) { oh[i] = bias3; ol[i] = 0.0f; }
#pragma unroll
            for (int kb = 0; kb < 4; ++kb) {
                oh = MFMA32(a3h[kb], w3h[kb], oh);
                ol = MFMA32(a3h[kb], w3l[kb], ol);
                ol = MFMA32(a3l[kb], w3h[kb], ol);
            }
            if (nv) {
#pragma unroll
                for (int i = 0; i < 16; ++i) {
                    float v = fmaf(ol[i], LO_SCALE, oh[i]);
                    int row = (i & 3) + 8 * (i >> 2) + 4 * g;
                    oreg[row * 8 + n5] = v;
                }
            }
        }
        __builtin_amdgcn_sched_barrier(0);

        // ---- quat normalize + store (lane r handles row r0+r) ----
        if (lane < 32) {
            int r = r0 + lane;
            if (r < nrows) {
                const floatx4* p = (const floatx4*)&oreg[lane * 8];
                floatx4 q0 = p[0], q1 = p[1];
                float s = fmaf(q0[3], q0[3],
                          fmaf(q1[0], q1[0],
                          fmaf(q1[1], q1[1], q1[2] * q1[2])));
                float rn = 1.0f / sqrtf(s);
                float* orow = out + (size_t)r * 7;
                orow[0] = q0[0];
                orow[1] = q0[1];
                orow[2] = q0[2];
                orow[3] = q0[3] * rn;
                orow[4] = q1[0] * rn;
                orow[5] = q1[1] * rn;
                orow[6] = q1[2] * rn;
            }
        }
        __builtin_amdgcn_sched_barrier(0);
    }
}

extern "C" void kernel_launch(void* const* d_in, const int* in_sizes, int n_in,
                              void* d_out, int out_size, void* d_ws, size_t ws_size,
                              hipStream_t stream)
{
    const float* x  = (const float*)d_in[0];
    const float* W1 = (const float*)d_in[1];
    const float* b1 = (const float*)d_in[2];
    const float* W2 = (const float*)d_in[3];
    const float* b2 = (const float*)d_in[4];
    const float* W3 = (const float*)d_in[5];
    const float* b3 = (const float*)d_in[6];
    float* out = (float*)d_out;

    const int nrows = in_sizes[0] / 7;
    const int grid  = (nrows + 1023) / 1024;  // 1024 rows per block (8 iters x 128)
    pose_mlp_mfma<<<grid, 256, 0, stream>>>(x, W1, b1, W2, b2, W3, b3, out, nrows);
}

// Round 7
// 114.934 us; speedup vs baseline: 2.6753x; 1.5761x over previous
//
#include <hip/hip_runtime.h>
#include <math.h>

// PoseMLP, fully-transposed register-resident split-f16 MFMA (R7 = R6 with
// compile fix: cvt_pkrtz returns __fp16x2, not _Float16x2).
//
// Everything computed transposed: h^T = W * X^T. A = weights (rows=neurons),
// B = activations (cols=batch). D (col=lane&31=batch, row=crow(i,g)=neuron)
// feeds the next layer's B-frag via: pkrtz-pack reg pairs -> lane<->lane+32
// half-exchange (__shfl_xor 32) -> word ordering select. No LDS at all.
//
// Split math (same error class as fp32, verified R5 absmax 0.0039):
//   a = hi + lo*2^-12; hi = RTZ_f16(a) (v_cvt_pkrtz packs 2/instr),
//   lo = RTZ_f16((a-hi)*4096). Kept: hihi->acc_h; hi*lo_s+lo_s*hi->acc_l;
//   result = acc_h + acc_l*2^-12.
// L1 bias folded into k=7 slot (B k7 = 1.0, A k7 = split(b1)).
//
// v_mfma_f32_32x32x16_f16 layouts (verified by R5 pass):
//   A: row=lane&31, k=8*(lane>>5)+j ; B: col=lane&31, k=8*(lane>>5)+j
//   D: col=lane&31, row=(i&3)+8*(i>>2)+4*(lane>>5)

typedef _Float16 half8  __attribute__((ext_vector_type(8)));
typedef __fp16   fp16x2 __attribute__((ext_vector_type(2)));
typedef float    floatx16 __attribute__((ext_vector_type(16)));

#define MFMA32(a, b, c) __builtin_amdgcn_mfma_f32_32x32x16_f16((a), (b), (c), 0, 0, 0)
#define LO_SCALE 2.44140625e-4f  /* 2^-12 */

union PairU { fp16x2 h; unsigned int u; };
union FragU { unsigned int w[4]; half8 h; };

// pack two floats' hi parts and lo parts: returns (hiWord, loWord)
static __device__ inline void split_pack2(float v0, float v1,
                                          unsigned int& hw, unsigned int& lw) {
    PairU hp, lp;
    hp.h = __builtin_amdgcn_cvt_pkrtz(v0, v1);          // 1 instr, RTZ
    float f0 = (float)hp.h[0], f1 = (float)hp.h[1];
    lp.h = __builtin_amdgcn_cvt_pkrtz((v0 - f0) * 4096.0f,
                                      (v1 - f1) * 4096.0f);
    hw = hp.u; lw = lp.u;
}

__global__ __launch_bounds__(256, 2) void pose_mlp_mfma_t(
    const float* __restrict__ x,
    const float* __restrict__ W1, const float* __restrict__ b1,
    const float* __restrict__ W2, const float* __restrict__ b2,
    const float* __restrict__ W3, const float* __restrict__ b3,
    float* __restrict__ out, int nrows)
{
    const int tid  = threadIdx.x;
    const int lane = tid & 63;
    const int wv   = tid >> 6;
    const int g    = lane >> 5;   // lane half (k-group / row-group)
    const int n5   = lane & 31;   // neuron row (for A) / batch col (for B/D)

    // ---------------- stationary A-frags (weights), per lane ----------------
    // W2: A[ct][kb]: row = ct*32+n5, k = kb*16 + g*8 + j
    half8 w2h[2][4], w2l[2][4];
#pragma unroll
    for (int ct = 0; ct < 2; ++ct) {
        const float* wrow = W2 + (ct * 32 + n5) * 64;
#pragma unroll
        for (int kb = 0; kb < 4; ++kb) {
            FragU H, L;
#pragma unroll
            for (int m = 0; m < 4; ++m) {
                float a0 = wrow[kb * 16 + g * 8 + 2 * m];
                float a1 = wrow[kb * 16 + g * 8 + 2 * m + 1];
                split_pack2(a0, a1, H.w[m], L.w[m]);
            }
            w2h[ct][kb] = H.h; w2l[ct][kb] = L.h;
        }
    }
    // W3: rows = out neurons (n5 < 7 valid)
    const bool nv = (n5 < 7);
    half8 w3h[4], w3l[4];
#pragma unroll
    for (int kb = 0; kb < 4; ++kb) {
        FragU H, L;
#pragma unroll
        for (int m = 0; m < 4; ++m) {
            float a0 = nv ? W3[n5 * 64 + kb * 16 + g * 8 + 2 * m] : 0.0f;
            float a1 = nv ? W3[n5 * 64 + kb * 16 + g * 8 + 2 * m + 1] : 0.0f;
            split_pack2(a0, a1, H.w[m], L.w[m]);
        }
        w3h[kb] = H.h; w3l[kb] = L.h;
    }
    // W1: k = g*8+j; g0 j<7 = weights, g0 j7 = bias (B k7 = 1.0), g1 = 0
    half8 w1h[2], w1l[2];
#pragma unroll
    for (int ct = 0; ct < 2; ++ct) {
        FragU H, L;
#pragma unroll
        for (int m = 0; m < 4; ++m) {
            int k0 = 2 * m, k1 = 2 * m + 1;
            float a0 = (g == 0) ? W1[(ct * 32 + n5) * 7 + k0] : 0.0f;
            float a1 = (g == 0) ? ((k1 < 7) ? W1[(ct * 32 + n5) * 7 + k1]
                                            : b1[ct * 32 + n5]) : 0.0f;
            split_pack2(a0, a1, H.w[m], L.w[m]);
        }
        w1h[ct] = H.h; w1l[ct] = L.h;
    }
    // bias tables (neuron = crow(i,g) per reg)
    float b2t[2][16];
#pragma unroll
    for (int ct = 0; ct < 2; ++ct)
#pragma unroll
        for (int i = 0; i < 16; ++i)
            b2t[ct][i] = b2[ct * 32 + (i & 3) + 8 * (i >> 2) + 4 * g];
    float b3t[4];
#pragma unroll
    for (int i = 0; i < 4; ++i)
        b3t[i] = g ? ((i < 3) ? b3[4 + i] : 0.0f) : b3[i];

    // ---------------- main loop: ITERS x 128 rows/block ----------------
    const int ITERS = 16;
    const int blk0 = blockIdx.x * (ITERS * 128);

    float xv[7] = {0.f,0.f,0.f,0.f,0.f,0.f,0.f};
    {
        int r = blk0 + wv * 32 + n5;
        if (g == 0 && r < nrows) {
            const float* xr = x + (size_t)r * 7;
#pragma unroll
            for (int j = 0; j < 7; ++j) xv[j] = xr[j];
        }
    }

    for (int it = 0; it < ITERS; ++it) {
        const int r0 = blk0 + it * 128 + wv * 32;

        // ---- X B-frag: col=n5 (batch), k=g*8+j; g0 j7 = 1.0 (bias slot) ----
        FragU xH, xL;
        {
            float p0 = g ? 0.f : xv[0], p1 = g ? 0.f : xv[1];
            float p2 = g ? 0.f : xv[2], p3 = g ? 0.f : xv[3];
            float p4 = g ? 0.f : xv[4], p5 = g ? 0.f : xv[5];
            float p6 = g ? 0.f : xv[6], p7 = g ? 0.f : 1.0f;
            split_pack2(p0, p1, xH.w[0], xL.w[0]);
            split_pack2(p2, p3, xH.w[1], xL.w[1]);
            split_pack2(p4, p5, xH.w[2], xL.w[2]);
            split_pack2(p6, p7, xH.w[3], xL.w[3]);
        }
        // prefetch next iter's X
        if (it < ITERS - 1) {
            int r = r0 + 128 + n5;
            if (g == 0 && r < nrows) {
                const float* xr = x + (size_t)r * 7;
#pragma unroll
                for (int j = 0; j < 7; ++j) xv[j] = xr[j];
            }
        }

        // ---- Layer 1 (transposed): h1^T[ct] ; pack owned words ----
        unsigned int ownH[2][8], ownL[2][8];
#pragma unroll
        for (int ct = 0; ct < 2; ++ct) {
            floatx16 ah, al;
#pragma unroll
            for (int i = 0; i < 16; ++i) { ah[i] = 0.0f; al[i] = 0.0f; }
            ah = MFMA32(w1h[ct], xH.h, ah);
            al = MFMA32(w1h[ct], xL.h, al);
            al = MFMA32(w1l[ct], xH.h, al);
#pragma unroll
            for (int m = 0; m < 8; ++m) {
                float v0 = fmaxf(fmaf(al[2*m],   LO_SCALE, ah[2*m]),   0.0f);
                float v1 = fmaxf(fmaf(al[2*m+1], LO_SCALE, ah[2*m+1]), 0.0f);
                split_pack2(v0, v1, ownH[ct][m], ownL[ct][m]);
            }
        }

        // ---- exchange -> B-frags for L2 ----
        half8 aH[4], aL[4];
#pragma unroll
        for (int kb = 0; kb < 4; ++kb) {
            const int c = kb >> 1, sA = (kb & 1) * 4, sB = sA + 2;
            unsigned int t0, t1, r0w, r1w;
            FragU H, L;
            t0 = g ? ownH[c][sA]   : ownH[c][sB];
            t1 = g ? ownH[c][sA+1] : ownH[c][sB+1];
            r0w = (unsigned int)__shfl_xor((int)t0, 32, 64);
            r1w = (unsigned int)__shfl_xor((int)t1, 32, 64);
            H.w[0] = g ? r0w : ownH[c][sA];   H.w[1] = g ? r1w : ownH[c][sA+1];
            H.w[2] = g ? ownH[c][sB] : r0w;   H.w[3] = g ? ownH[c][sB+1] : r1w;
            t0 = g ? ownL[c][sA]   : ownL[c][sB];
            t1 = g ? ownL[c][sA+1] : ownL[c][sB+1];
            r0w = (unsigned int)__shfl_xor((int)t0, 32, 64);
            r1w = (unsigned int)__shfl_xor((int)t1, 32, 64);
            L.w[0] = g ? r0w : ownL[c][sA];   L.w[1] = g ? r1w : ownL[c][sA+1];
            L.w[2] = g ? ownL[c][sB] : r0w;   L.w[3] = g ? ownL[c][sB+1] : r1w;
            aH[kb] = H.h; aL[kb] = L.h;
        }

        // ---- Layer 2 (transposed): h2^T ; pack owned words ----
#pragma unroll
        for (int ct = 0; ct < 2; ++ct) {
            floatx16 ch, cl;
#pragma unroll
            for (int i = 0; i < 16; ++i) { ch[i] = b2t[ct][i]; cl[i] = 0.0f; }
#pragma unroll
            for (int kb = 0; kb < 4; ++kb) {
                ch = MFMA32(w2h[ct][kb], aH[kb], ch);
                cl = MFMA32(w2h[ct][kb], aL[kb], cl);
                cl = MFMA32(w2l[ct][kb], aH[kb], cl);
            }
#pragma unroll
            for (int m = 0; m < 8; ++m) {
                float v0 = fmaxf(fmaf(cl[2*m],   LO_SCALE, ch[2*m]),   0.0f);
                float v1 = fmaxf(fmaf(cl[2*m+1], LO_SCALE, ch[2*m+1]), 0.0f);
                split_pack2(v0, v1, ownH[ct][m], ownL[ct][m]);
            }
        }

        // ---- exchange -> B-frags for L3 ----
#pragma unroll
        for (int kb = 0; kb < 4; ++kb) {
            const int c = kb >> 1, sA = (kb & 1) * 4, sB = sA + 2;
            unsigned int t0, t1, r0w, r1w;
            FragU H, L;
            t0 = g ? ownH[c][sA]   : ownH[c][sB];
            t1 = g ? ownH[c][sA+1] : ownH[c][sB+1];
            r0w = (unsigned int)__shfl_xor((int)t0, 32, 64);
            r1w = (unsigned int)__shfl_xor((int)t1, 32, 64);
            H.w[0] = g ? r0w : ownH[c][sA];   H.w[1] = g ? r1w : ownH[c][sA+1];
            H.w[2] = g ? ownH[c][sB] : r0w;   H.w[3] = g ? ownH[c][sB+1] : r1w;
            t0 = g ? ownL[c][sA]   : ownL[c][sB];
            t1 = g ? ownL[c][sA+1] : ownL[c][sB+1];
            r0w = (unsigned int)__shfl_xor((int)t0, 32, 64);
            r1w = (unsigned int)__shfl_xor((int)t1, 32, 64);
            L.w[0] = g ? r0w : ownL[c][sA];   L.w[1] = g ? r1w : ownL[c][sA+1];
            L.w[2] = g ? ownL[c][sB] : r0w;   L.w[3] = g ? ownL[c][sB+1] : r1w;
            aH[kb] = H.h; aL[kb] = L.h;
        }

        // ---- Layer 3 (transposed): o^T rows 0..6 ----
        {
            floatx16 oh, ol;
#pragma unroll
            for (int i = 0; i < 16; ++i) { oh[i] = 0.0f; ol[i] = 0.0f; }
#pragma unroll
            for (int kb = 0; kb < 4; ++kb) {
                oh = MFMA32(w3h[kb], aH[kb], oh);
                ol = MFMA32(w3h[kb], aL[kb], ol);
                ol = MFMA32(w3l[kb], aH[kb], ol);
            }
            // g0 regs 0..3 = o0..o3 ; g1 regs 0..2 = o4..o6
            float c0 = fmaf(ol[0], LO_SCALE, oh[0]) + b3t[0];
            float c1 = fmaf(ol[1], LO_SCALE, oh[1]) + b3t[1];
            float c2 = fmaf(ol[2], LO_SCALE, oh[2]) + b3t[2];
            float c3 = fmaf(ol[3], LO_SCALE, oh[3]) + b3t[3];

            float p = g ? fmaf(c2, c2, fmaf(c1, c1, c0 * c0)) : c3 * c3;
            float s = p + __shfl_xor(p, 32, 64);
            float rn = 1.0f / sqrtf(s);

            int r = r0 + n5;
            if (r < nrows) {
                float* orow = out + (size_t)r * 7;
                if (g == 0) {
                    orow[0] = c0; orow[1] = c1; orow[2] = c2; orow[3] = c3 * rn;
                } else {
                    orow[4] = c0 * rn; orow[5] = c1 * rn; orow[6] = c2 * rn;
                }
            }
        }
    }
}

extern "C" void kernel_launch(void* const* d_in, const int* in_sizes, int n_in,
                              void* d_out, int out_size, void* d_ws, size_t ws_size,
                              hipStream_t stream)
{
    const float* x  = (const float*)d_in[0];
    const float* W1 = (const float*)d_in[1];
    const float* b1 = (const float*)d_in[2];
    const float* W2 = (const float*)d_in[3];
    const float* b2 = (const float*)d_in[4];
    const float* W3 = (const float*)d_in[5];
    const float* b3 = (const float*)d_in[6];
    float* out = (float*)d_out;

    const int nrows = in_sizes[0] / 7;
    const int rows_per_block = 16 * 128;  // ITERS * 128
    const int grid = (nrows + rows_per_block - 1) / rows_per_block;
    pose_mlp_mfma_t<<<grid, 256, 0, stream>>>(x, W1, b1, W2, b2, W3, b3, out, nrows);
}

// Round 9
// 100.748 us; speedup vs baseline: 3.0520x; 1.1408x over previous
//
#include <hip/hip_runtime.h>
#include <math.h>

// PoseMLP, transposed register-resident split-f16 MFMA + permlane32_swap
// exchanges (R9 = R8 resubmit; container infra died, no data).
// R7 was latency-bound (134us @ VALUBusy 56%, occupancy 19.5%):
// 32 ds_bpermute (__shfl_xor) + ~160 cndmask per iter on the critical path.
// v_permlane32_swap_b32 (d,s) -> d'={d.lo32,s.lo32}, s'={d.hi32,s.hi32}
// (ISA: VDST.row[1] <-> VSRC.row[0]) is exactly the 2x2 half-block transpose
// the layer transition needs: one instr produces TWO B-frag words, no DS.
//
// Split math (verified R5/R7, absmax 0.0039 = fp32 class):
//   a = hi + lo*2^-12; hi = RTZ_f16(a), lo = RTZ_f16((a-hi)*4096).
//   acc_h += hi*hi ; acc_l += hi*lo_s + lo_s*hi ; result = acc_h + acc_l*2^-12.
// L1 bias folded into k=7 slot (B k7 = 1.0, A k7 = split(b1)).
//
// v_mfma_f32_32x32x16_f16 layouts (verified R5/R7):
//   A: row=lane&31, k=8*(lane>>5)+j ; B: col=lane&31, k=8*(lane>>5)+j
//   D: col=lane&31, row=(i&3)+8*(i>>2)+4*(lane>>5)

typedef _Float16 half8  __attribute__((ext_vector_type(8)));
typedef __fp16   fp16x2 __attribute__((ext_vector_type(2)));
typedef float    floatx16 __attribute__((ext_vector_type(16)));
typedef unsigned int uint2v __attribute__((ext_vector_type(2)));

#define MFMA32(a, b, c) __builtin_amdgcn_mfma_f32_32x32x16_f16((a), (b), (c), 0, 0, 0)
#define LO_SCALE 2.44140625e-4f  /* 2^-12 */

union PairU { fp16x2 h; unsigned int u; };
union FragU { unsigned int w[4]; half8 h; };

// pack two floats' hi parts and lo parts: returns (hiWord, loWord)
static __device__ inline void split_pack2(float v0, float v1,
                                          unsigned int& hw, unsigned int& lw) {
    PairU hp, lp;
    hp.h = __builtin_amdgcn_cvt_pkrtz(v0, v1);          // 1 instr, RTZ
    float f0 = (float)hp.h[0], f1 = (float)hp.h[1];
    lp.h = __builtin_amdgcn_cvt_pkrtz((v0 - f0) * 4096.0f,
                                      (v1 - f1) * 4096.0f);
    hw = hp.u; lw = lp.u;
}

// 2x2 half-block transpose: lo = {a.lanes<32, b.lanes<32}, hi = {a.lanes>=32, b.lanes>=32}
static __device__ inline void swap32(unsigned int a, unsigned int b,
                                     unsigned int& lo, unsigned int& hi) {
    uint2v r = __builtin_amdgcn_permlane32_swap(a, b, false, false);
    lo = r[0]; hi = r[1];
}

__global__ __launch_bounds__(256, 2) void pose_mlp_mfma_t(
    const float* __restrict__ x,
    const float* __restrict__ W1, const float* __restrict__ b1,
    const float* __restrict__ W2, const float* __restrict__ b2,
    const float* __restrict__ W3, const float* __restrict__ b3,
    float* __restrict__ out, int nrows)
{
    const int tid  = threadIdx.x;
    const int lane = tid & 63;
    const int wv   = tid >> 6;
    const int g    = lane >> 5;   // lane half (k-group / row-group)
    const int n5   = lane & 31;   // neuron row (for A) / batch col (for B/D)

    // ---------------- stationary A-frags (weights), per lane ----------------
    // W2: A[ct][kb]: row = ct*32+n5, k = kb*16 + g*8 + j
    half8 w2h[2][4], w2l[2][4];
#pragma unroll
    for (int ct = 0; ct < 2; ++ct) {
        const float* wrow = W2 + (ct * 32 + n5) * 64;
#pragma unroll
        for (int kb = 0; kb < 4; ++kb) {
            FragU H, L;
#pragma unroll
            for (int m = 0; m < 4; ++m) {
                float a0 = wrow[kb * 16 + g * 8 + 2 * m];
                float a1 = wrow[kb * 16 + g * 8 + 2 * m + 1];
                split_pack2(a0, a1, H.w[m], L.w[m]);
            }
            w2h[ct][kb] = H.h; w2l[ct][kb] = L.h;
        }
    }
    // W3: rows = out neurons (n5 < 7 valid)
    const bool nv = (n5 < 7);
    half8 w3h[4], w3l[4];
#pragma unroll
    for (int kb = 0; kb < 4; ++kb) {
        FragU H, L;
#pragma unroll
        for (int m = 0; m < 4; ++m) {
            float a0 = nv ? W3[n5 * 64 + kb * 16 + g * 8 + 2 * m] : 0.0f;
            float a1 = nv ? W3[n5 * 64 + kb * 16 + g * 8 + 2 * m + 1] : 0.0f;
            split_pack2(a0, a1, H.w[m], L.w[m]);
        }
        w3h[kb] = H.h; w3l[kb] = L.h;
    }
    // W1: k = g*8+j; g0 j<7 = weights, g0 j7 = bias (B k7 = 1.0), g1 = 0
    half8 w1h[2], w1l[2];
#pragma unroll
    for (int ct = 0; ct < 2; ++ct) {
        FragU H, L;
#pragma unroll
        for (int m = 0; m < 4; ++m) {
            int k0 = 2 * m, k1 = 2 * m + 1;
            float a0 = (g == 0) ? W1[(ct * 32 + n5) * 7 + k0] : 0.0f;
            float a1 = (g == 0) ? ((k1 < 7) ? W1[(ct * 32 + n5) * 7 + k1]
                                            : b1[ct * 32 + n5]) : 0.0f;
            split_pack2(a0, a1, H.w[m], L.w[m]);
        }
        w1h[ct] = H.h; w1l[ct] = L.h;
    }
    // bias tables (neuron = crow(i,g) per reg)
    float b2t[2][16];
#pragma unroll
    for (int ct = 0; ct < 2; ++ct)
#pragma unroll
        for (int i = 0; i < 16; ++i)
            b2t[ct][i] = b2[ct * 32 + (i & 3) + 8 * (i >> 2) + 4 * g];
    float b3t[4];
#pragma unroll
    for (int i = 0; i < 4; ++i)
        b3t[i] = g ? ((i < 3) ? b3[4 + i] : 0.0f) : b3[i];

    // ---------------- main loop: ITERS x 128 rows/block ----------------
    const int ITERS = 16;
    const int blk0 = blockIdx.x * (ITERS * 128);

    float xv[7] = {0.f,0.f,0.f,0.f,0.f,0.f,0.f};
    {
        int r = blk0 + wv * 32 + n5;
        if (g == 0 && r < nrows) {
            const float* xr = x + (size_t)r * 7;
#pragma unroll
            for (int j = 0; j < 7; ++j) xv[j] = xr[j];
        }
    }

    for (int it = 0; it < ITERS; ++it) {
        const int r0 = blk0 + it * 128 + wv * 32;

        // ---- X B-frag: col=n5 (batch), k=g*8+j; g0 j7 = 1.0 (bias slot) ----
        FragU xH, xL;
        {
            float p0 = g ? 0.f : xv[0], p1 = g ? 0.f : xv[1];
            float p2 = g ? 0.f : xv[2], p3 = g ? 0.f : xv[3];
            float p4 = g ? 0.f : xv[4], p5 = g ? 0.f : xv[5];
            float p6 = g ? 0.f : xv[6], p7 = g ? 0.f : 1.0f;
            split_pack2(p0, p1, xH.w[0], xL.w[0]);
            split_pack2(p2, p3, xH.w[1], xL.w[1]);
            split_pack2(p4, p5, xH.w[2], xL.w[2]);
            split_pack2(p6, p7, xH.w[3], xL.w[3]);
        }
        // prefetch next iter's X
        if (it < ITERS - 1) {
            int r = r0 + 128 + n5;
            if (g == 0 && r < nrows) {
                const float* xr = x + (size_t)r * 7;
#pragma unroll
                for (int j = 0; j < 7; ++j) xv[j] = xr[j];
            }
        }

        // ---- Layer 1 (transposed): h1^T[ct] ; pack owned words ----
        unsigned int ownH[2][8], ownL[2][8];
#pragma unroll
        for (int ct = 0; ct < 2; ++ct) {
            floatx16 ah, al;
#pragma unroll
            for (int i = 0; i < 16; ++i) { ah[i] = 0.0f; al[i] = 0.0f; }
            ah = MFMA32(w1h[ct], xH.h, ah);
            al = MFMA32(w1h[ct], xL.h, al);
            al = MFMA32(w1l[ct], xH.h, al);
#pragma unroll
            for (int m = 0; m < 8; ++m) {
                float v0 = fmaxf(fmaf(al[2*m],   LO_SCALE, ah[2*m]),   0.0f);
                float v1 = fmaxf(fmaf(al[2*m+1], LO_SCALE, ah[2*m+1]), 0.0f);
                split_pack2(v0, v1, ownH[ct][m], ownL[ct][m]);
            }
        }

        // ---- exchange -> B-frags for L2 (permlane32_swap, no DS) ----
        half8 aH[4], aL[4];
#pragma unroll
        for (int kb = 0; kb < 4; ++kb) {
            const int c = kb >> 1, sA = (kb & 1) * 4, sB = sA + 2;
            FragU H, L;
            swap32(ownH[c][sA],   ownH[c][sB],   H.w[0], H.w[2]);
            swap32(ownH[c][sA+1], ownH[c][sB+1], H.w[1], H.w[3]);
            swap32(ownL[c][sA],   ownL[c][sB],   L.w[0], L.w[2]);
            swap32(ownL[c][sA+1], ownL[c][sB+1], L.w[1], L.w[3]);
            aH[kb] = H.h; aL[kb] = L.h;
        }

        // ---- Layer 2 (transposed): h2^T ; pack owned words ----
#pragma unroll
        for (int ct = 0; ct < 2; ++ct) {
            floatx16 ch, cl;
#pragma unroll
            for (int i = 0; i < 16; ++i) { ch[i] = b2t[ct][i]; cl[i] = 0.0f; }
#pragma unroll
            for (int kb = 0; kb < 4; ++kb) {
                ch = MFMA32(w2h[ct][kb], aH[kb], ch);
                cl = MFMA32(w2h[ct][kb], aL[kb], cl);
                cl = MFMA32(w2l[ct][kb], aH[kb], cl);
            }
#pragma unroll
            for (int m = 0; m < 8; ++m) {
                float v0 = fmaxf(fmaf(cl[2*m],   LO_SCALE, ch[2*m]),   0.0f);
                float v1 = fmaxf(fmaf(cl[2*m+1], LO_SCALE, ch[2*m+1]), 0.0f);
                split_pack2(v0, v1, ownH[ct][m], ownL[ct][m]);
            }
        }

        // ---- exchange -> B-frags for L3 ----
#pragma unroll
        for (int kb = 0; kb < 4; ++kb) {
            const int c = kb >> 1, sA = (kb & 1) * 4, sB = sA + 2;
            FragU H, L;
            swap32(ownH[c][sA],   ownH[c][sB],   H.w[0], H.w[2]);
            swap32(ownH[c][sA+1], ownH[c][sB+1], H.w[1], H.w[3]);
            swap32(ownL[c][sA],   ownL[c][sB],   L.w[0], L.w[2]);
            swap32(ownL[c][sA+1], ownL[c][sB+1], L.w[1], L.w[3]);
            aH[kb] = H.h; aL[kb] = L.h;
        }

        // ---- Layer 3 (transposed): o^T rows 0..6 ----
        {
            floatx16 oh, ol;
#pragma unroll
            for (int i = 0; i < 16; ++i) { oh[i] = 0.0f; ol[i] = 0.0f; }
#pragma unroll
            for (int kb = 0; kb < 4; ++kb) {
                oh = MFMA32(w3h[kb], aH[kb], oh);
                ol = MFMA32(w3h[kb], aL[kb], ol);
                ol = MFMA32(w3l[kb], aH[kb], ol);
            }
            // g0 regs 0..3 = o0..o3 ; g1 regs 0..2 = o4..o6
            float c0 = fmaf(ol[0], LO_SCALE, oh[0]) + b3t[0];
            float c1 = fmaf(ol[1], LO_SCALE, oh[1]) + b3t[1];
            float c2 = fmaf(ol[2], LO_SCALE, oh[2]) + b3t[2];
            float c3 = fmaf(ol[3], LO_SCALE, oh[3]) + b3t[3];

            float p = g ? fmaf(c2, c2, fmaf(c1, c1, c0 * c0)) : c3 * c3;
            unsigned int plo, phi;
            swap32(__float_as_uint(p), __float_as_uint(p), plo, phi);
            // g0 lanes need p from upper half (phi); g1 lanes need lower (plo)
            float other = __uint_as_float(g ? plo : phi);
            float s = p + other;
            float rn = 1.0f / sqrtf(s);

            int r = r0 + n5;
            if (r < nrows) {
                float* orow = out + (size_t)r * 7;
                if (g == 0) {
                    orow[0] = c0; orow[1] = c1; orow[2] = c2; orow[3] = c3 * rn;
                } else {
                    orow[4] = c0 * rn; orow[5] = c1 * rn; orow[6] = c2 * rn;
                }
            }
        }
    }
}

extern "C" void kernel_launch(void* const* d_in, const int* in_sizes, int n_in,
                              void* d_out, int out_size, void* d_ws, size_t ws_size,
                              hipStream_t stream)
{
    const float* x  = (const float*)d_in[0];
    const float* W1 = (const float*)d_in[1];
    const float* b1 = (const float*)d_in[2];
    const float* W2 = (const float*)d_in[3];
    const float* b2 = (const float*)d_in[4];
    const float* W3 = (const float*)d_in[5];
    const float* b3 = (const float*)d_in[6];
    float* out = (float*)d_out;

    const int nrows = in_sizes[0] / 7;
    const int rows_per_block = 16 * 128;  // ITERS * 128
    const int grid = (nrows + rows_per_block - 1) / rows_per_block;
    pose_mlp_mfma_t<<<grid, 256, 0, stream>>>(x, W1, b1, W2, b2, W3, b3, out, nrows);
}